// Round 1
// baseline (364.212 us; speedup 1.0000x reference)
//
#include <hip/hip_runtime.h>

// MSDeformAttn fusion, MI355X. Round 10: conv path = verbatim R4 conv_core
// (allocator-stable); NEW: XCD-static work schedule for conv_main/conv_out_k.
// Theory: conv was L3-BW-bound on weight re-fetch (1.3 GB VMEM weight traffic
// @ ~8.4 TB/s = 160us). Pinning each (img,mb) weight slice to one XCD makes
// re-reads L2-resident (slice 1.77MB + 256KB/kb pixel slab << 4MB L2/XCD).
// Traffic balanced: XCD0-5 = 1 qconv group + 48 value rows (~166MB),
// XCD6-7 = 240 value rows (~166MB).
// B=2, T=3, C=256, H=W=64, M=8, P=4, DH=32.

#define HW_SZ 4096

typedef __attribute__((ext_vector_type(8))) short short8;
typedef __attribute__((ext_vector_type(4))) float f32x4;

__device__ __forceinline__ unsigned short f2bf(float f) {
    union { float f; unsigned u; } v; v.f = f;
    unsigned u = v.u;
    unsigned r = (u + 0x7FFFu + ((u >> 16) & 1u)) >> 16;
    return (unsigned short)r;
}
__device__ __forceinline__ float bf2f(unsigned short h) {
    union { unsigned u; float f; } v; v.u = ((unsigned)h) << 16;
    return v.f;
}

__device__ __forceinline__ void gld16(const void* g, void* l) {
    __builtin_amdgcn_global_load_lds(
        (const __attribute__((address_space(1))) unsigned*)g,
        (__attribute__((address_space(3))) unsigned*)l, 16, 0, 0);
}

// ---------------- fused prep: transposes + weight repacks + biases ----------------
// repack thread = (oc, kb, lg): reads 8 ic x 9 taps contiguous, writes 9 fragments
// to wpk [tap][ob][kb][64][8]. oc in [Cout, OBp*16) zero-fills (pad slots).
__device__ __forceinline__ void repack2(
    int g, const float* __restrict__ w0, const float* __restrict__ w1,
    int split, int Cout, int Cin, unsigned short* __restrict__ out, int OBp)
{
    int lg = g & 3; int rest = g >> 2;
    int KB = Cin >> 5;
    int kb = rest % KB; int oc = rest / KB;
    int ob = oc >> 4, l16 = oc & 15;
    if (oc >= Cout) {
        uint4 z; z.x = z.y = z.z = z.w = 0u;
        #pragma unroll
        for (int tap = 0; tap < 9; ++tap)
            *(uint4*)(out + (((size_t)tap * OBp + ob) * KB + kb) * 512 + (lg * 16 + l16) * 8) = z;
        return;
    }
    const float* src = (oc < split)
        ? (w0 + ((size_t)oc * Cin + kb * 32 + lg * 8) * 9)
        : (w1 + ((size_t)(oc - split) * Cin + kb * 32 + lg * 8) * 9);
    float v[8][9];
    #pragma unroll
    for (int i = 0; i < 8; ++i)
        #pragma unroll
        for (int t = 0; t < 9; ++t)
            v[i][t] = src[i * 9 + t];
    #pragma unroll
    for (int tap = 0; tap < 9; ++tap) {
        unsigned p[4];
        #pragma unroll
        for (int j = 0; j < 4; ++j)
            p[j] = (unsigned)f2bf(v[2 * j][tap]) | ((unsigned)f2bf(v[2 * j + 1][tap]) << 16);
        uint4 o; o.x = p[0]; o.y = p[1]; o.z = p[2]; o.w = p[3];
        *(uint4*)(out + (((size_t)tap * OBp + ob) * KB + kb) * 512 + (lg * 16 + l16) * 8) = o;
    }
}

__global__ __launch_bounds__(256) void prep_fused(
    const float* __restrict__ vin_src, const float* __restrict__ qin_src,
    unsigned short* __restrict__ vdst, unsigned short* __restrict__ qdst,
    const float* __restrict__ w_value, const float* __restrict__ w_off,
    const float* __restrict__ w_attn, const float* __restrict__ w_out,
    const float* __restrict__ b_off, const float* __restrict__ b_attn,
    unsigned short* __restrict__ wpk_v, unsigned short* __restrict__ wpk_q,
    unsigned short* __restrict__ wpk_o, float* __restrict__ qbias,
    float* __restrict__ zbuf)
{
    int bid = blockIdx.x;
    if (bid < 6144) {
        int y = bid & 63, z = bid >> 6;
        const float* in; unsigned short* out; int Cin, img, kb;
        if (z < 48) { img = z >> 3; kb = z & 7; in = vin_src; out = vdst; Cin = 256; }
        else { int h = z - 48; img = h / 24; kb = h % 24; in = qin_src; out = qdst; Cin = 768; }
        __shared__ float s[32][65];
        int t = threadIdx.x;
        int x = t & 63, ic4 = t >> 6;
        const float* ip = in + ((size_t)img * Cin + kb * 32) * HW_SZ + y * 64;
        #pragma unroll
        for (int i = 0; i < 8; ++i) {
            int icl = ic4 * 8 + i;
            s[icl][x] = ip[(size_t)icl * HW_SZ + x];
        }
        __syncthreads();
        int p = t >> 2, h4 = t & 3;
        unsigned v[4];
        #pragma unroll
        for (int j = 0; j < 4; ++j) {
            unsigned lo = f2bf(s[h4 * 8 + 2 * j][p]);
            unsigned hi = f2bf(s[h4 * 8 + 2 * j + 1][p]);
            v[j] = lo | (hi << 16);
        }
        uint4 o; o.x = v[0]; o.y = v[1]; o.z = v[2]; o.w = v[3];
        *(uint4*)(out + ((size_t)img * HW_SZ + y * 64 + p) * Cin + kb * 32 + h4 * 8) = o;
    } else {
        int g = (bid - 6144) * 256 + threadIdx.x;
        if (g < 8192) {
            repack2(g, w_value, w_value, 256, 256, 256, wpk_v, 16);
        } else if (g < 45056) {                                  // 384 oc x 24 kb x 4
            repack2(g - 8192, w_off, w_attn, 192, 288, 768, wpk_q, 24);
        } else if (g < 53248) {
            repack2(g - 45056, w_out, w_out, 256, 256, 256, wpk_o, 16);
        } else {
            int i = g - 53248;
            if (i < 16) zbuf[i] = 0.f;
            if (i < 384) {
                float v = 0.f;
                if (i < 192) v = b_off[i]; else if (i < 288) v = b_attn[i - 192];
                qbias[i] = v;
            }
        }
    }
}

// ---------------- MFMA conv core (VERBATIM R4 — allocator-stable) ----------------
// Block: 128 thr = 2 waves; wave wv = oc half. Tile: 128 oc x 64 px (row y0).
// LDS: 2 buffers x [3 rows][4 icg][66 cols] 16B units = 2 x 12672 B.
// Weight frags: rolling 3-tap register prefetch (afr[3][4]).
__device__ __forceinline__ void conv_core(
    const unsigned short* __restrict__ gin,
    const unsigned short* __restrict__ wpk,   // [9][OBp][KB][64][8]
    const float* __restrict__ bias,
    const unsigned short* __restrict__ zbuf,
    void* __restrict__ outp,
    int Cin, int KB, int OBp, int Cout, int mb, int y0, int outmode, int img,
    unsigned short* sbuf)
{
    const int tid = threadIdx.x;
    const int wv = tid >> 6, lane = tid & 63;
    const int l16 = lane & 15, lg = lane >> 4;
    const int obBase = mb * 8 + wv * 4;

    // precompute staging sources; wave wv takes issues ii = 2i+wv (13 total)
    const unsigned short* sptr[7];
    int okk[7];
    #pragma unroll
    for (int i = 0; i < 7; ++i) {
        int ii = 2 * i + wv;
        int r = ii * 64 + lane;
        sptr[i] = zbuf; okk[i] = 0;
        if (ii < 13 && r < 792) {
            int rr = r / 264;
            int rem = r - rr * 264;
            int icg = rem / 66;
            int cc = rem - icg * 66;
            int gy = y0 - 1 + rr, gx = cc - 1;
            if ((unsigned)gy < 64u && (unsigned)gx < 64u) {
                sptr[i] = gin + ((size_t)(gy * 64 + gx)) * Cin + icg * 8;
                okk[i] = 1;
            }
        }
    }

    f32x4 acc[4][4];
    #pragma unroll
    for (int a = 0; a < 4; ++a)
        #pragma unroll
        for (int b = 0; b < 4; ++b)
            acc[a][b] = (f32x4){0.f, 0.f, 0.f, 0.f};

    auto stage = [&](int kb, unsigned short* sb) {
        #pragma unroll
        for (int i = 0; i < 7; ++i) {
            int ii = 2 * i + wv;
            int r = ii * 64 + lane;
            if (ii < 13 && r < 792) {
                const unsigned short* s = sptr[i] + (okk[i] ? (size_t)kb * 32 : 0);
                gld16(s, sb + (size_t)ii * 64 * 8);
            }
        }
    };

    short8 afr[3][4];
    auto ldA = [&](int kb, int tap, int slot) {
        const unsigned short* wp =
            wpk + (((size_t)tap * OBp + obBase) * KB + kb) * 512;
        #pragma unroll
        for (int ob = 0; ob < 4; ++ob)
            afr[slot][ob] = *(const short8*)(wp + (size_t)ob * KB * 512 + lane * 8);
    };

    stage(0, sbuf);
    for (int kb = 0; kb < KB; ++kb) {
        __syncthreads();                       // buffer kb ready (drains vmcnt)
        if (kb + 1 < KB) stage(kb + 1, sbuf + ((kb + 1) & 1) * 6336);
        ldA(kb, 0, 0); ldA(kb, 1, 1); ldA(kb, 2, 2);
        const unsigned short* cb = sbuf + (kb & 1) * 6336;
        #pragma unroll
        for (int tap = 0; tap < 9; ++tap) {
            const int ky = tap / 3, kx = tap % 3;
            const int slot = tap % 3;
            short8 bfr[4];
            #pragma unroll
            for (int pt = 0; pt < 4; ++pt)
                bfr[pt] = *(const short8*)(cb + (ky * 264 + lg * 66 + kx + pt * 16 + l16) * 8);
            #pragma unroll
            for (int ob = 0; ob < 4; ++ob)
                #pragma unroll
                for (int pt = 0; pt < 4; ++pt)
                    acc[ob][pt] = __builtin_amdgcn_mfma_f32_16x16x32_bf16(
                        afr[slot][ob], bfr[pt], acc[ob][pt], 0, 0, 0);
            if (tap < 6) ldA(kb, tap + 3, slot);
        }
    }

    if (outmode == 2) {
        float* outf = (float*)outp + (size_t)img * 256 * HW_SZ + (size_t)y0 * 64;
        #pragma unroll
        for (int ob = 0; ob < 4; ++ob) {
            int obg = obBase + ob;
            #pragma unroll
            for (int r = 0; r < 4; ++r) {
                int oc = obg * 16 + lg * 4 + r;
                float bv = bias[oc];
                #pragma unroll
                for (int pt = 0; pt < 4; ++pt)
                    outf[(size_t)oc * HW_SZ + pt * 16 + l16] = acc[ob][pt][r] + bv;
            }
        }
    } else {
        __syncthreads();                       // LDS reads done; reuse for epilogue
        float* s_ep = (float*)sbuf + wv * 1088;  // per-wave 64px x 17
        for (int ob = 0; ob < 4; ++ob) {
            int obg = obBase + ob;
            if (obg * 16 >= Cout) continue;    // wave-uniform
            #pragma unroll
            for (int r = 0; r < 4; ++r) {
                float bv = bias ? bias[obg * 16 + lg * 4 + r] : 0.f;
                #pragma unroll
                for (int pt = 0; pt < 4; ++pt)
                    s_ep[(pt * 16 + l16) * 17 + lg * 4 + r] = acc[ob][pt][r] + bv;
            }
            size_t pxg = (size_t)img * HW_SZ + (size_t)y0 * 64 + lane;
            if (outmode == 1) {
                float* op = (float*)outp + pxg * 288 + obg * 16;
                #pragma unroll
                for (int jj = 0; jj < 4; ++jj) {
                    float4 t4;
                    t4.x = s_ep[lane * 17 + jj * 4 + 0];
                    t4.y = s_ep[lane * 17 + jj * 4 + 1];
                    t4.z = s_ep[lane * 17 + jj * 4 + 2];
                    t4.w = s_ep[lane * 17 + jj * 4 + 3];
                    *(float4*)(op + jj * 4) = t4;
                }
            } else {
                unsigned short* op = (unsigned short*)outp + pxg * 256 + obg * 16;
                unsigned v[8];
                #pragma unroll
                for (int j = 0; j < 8; ++j) {
                    unsigned lo = f2bf(s_ep[lane * 17 + 2 * j]);
                    unsigned hi = f2bf(s_ep[lane * 17 + 2 * j + 1]);
                    v[j] = lo | (hi << 16);
                }
                uint4 o0; o0.x = v[0]; o0.y = v[1]; o0.z = v[2]; o0.w = v[3];
                uint4 o1; o1.x = v[4]; o1.y = v[5]; o1.z = v[6]; o1.w = v[7];
                *(uint4*)(op) = o0;
                *(uint4*)(op + 8) = o1;
            }
        }
    }
}

// merged value+qconv.
// ybase >= 0 (legacy / small-ws path): g = ybase + blockIdx.y, y0 = blockIdx.x:
//   g in [0,6):  qconv  img=g/3, mb=g%3  (768->288, f32 pm)  -- heavy, first
//   g in [6,18): value  img=(g-6)>>1, mb=(g-6)&1 (256->256, bf16 pm)
// ybase < 0 (big path): XCD-static schedule, 1-D grid of 1920, assumes
//   blockIdx.x % 8 == XCD. XCD x in [0,6): all 64 rows of qconv group g=x
//   (weight slice 1.77MB pinned in that XCD's L2) + 48 value rows.
//   XCD 6,7: 240 value rows each. Traffic ~166MB/XCD, balanced.
__global__ __launch_bounds__(128, 2) void conv_main(
    int ybase,
    const unsigned short* __restrict__ vin, const unsigned short* __restrict__ wv_,
    const float* __restrict__ bv, unsigned short* __restrict__ vout,
    const unsigned short* __restrict__ qin, const unsigned short* __restrict__ wq_,
    const float* __restrict__ bq, float* __restrict__ qout,
    const unsigned short* __restrict__ zbuf)
{
    __shared__ __align__(16) unsigned short sbuf[2 * 6336];
    int g, y0;
    if (ybase < 0) {
        int xcd = blockIdx.x & 7, idx = blockIdx.x >> 3;   // grid = 1920 = 8*240
        if (xcd < 6) {
            if (idx < 64) { g = xcd; y0 = idx; }           // qconv group x, row idx
            else if (idx < 112) {                          // 48 value rows
                int v = xcd * 48 + (idx - 64);
                g = 6 + (v >> 6); y0 = v & 63;
            } else {
                return;                                    // idle pad block
            }
        } else {                                           // 240 value rows each
            int v = 288 + (xcd - 6) * 240 + idx;
            g = 6 + (v >> 6); y0 = v & 63;
        }
    } else {
        g = ybase + blockIdx.y;
        y0 = blockIdx.x;
    }
    if (g < 6) {
        int img = g / 3, mb = g - img * 3;
        conv_core(qin + (size_t)img * HW_SZ * 768, wq_, bq, zbuf, (void*)qout,
                  768, 24, 24, 288, mb, y0, 1, img, sbuf);
    } else {
        int h = g - 6; int img = h >> 1, mb = h & 1;
        conv_core(vin + (size_t)img * HW_SZ * 256, wv_, bv, zbuf, (void*)vout,
                  256, 8, 16, 256, mb, y0, 0, img, sbuf);
    }
}

// out conv: 1-D grid of 256, XCD-static: xcd pair shares one (img,mb) group,
// each xcd covers 32 rows. NCHW f32 -> d_out.
__global__ __launch_bounds__(128, 2) void conv_out_k(
    const unsigned short* __restrict__ din, const unsigned short* __restrict__ wo_,
    const float* __restrict__ bo, float* __restrict__ outp,
    const unsigned short* __restrict__ zbuf)
{
    __shared__ __align__(16) unsigned short sbuf[2 * 6336];
    int xcd = blockIdx.x & 7, idx = blockIdx.x >> 3;       // idx 0..31
    int g = xcd >> 1;                                      // 0..3
    int y0 = (xcd & 1) * 32 + idx;
    int img = g >> 1, mb = g & 1;
    conv_core(din + (size_t)img * HW_SZ * 256, wo_, bo, zbuf, (void*)outp,
              256, 8, 16, 256, mb, y0, 2, img, sbuf);
}

// ---------------- deform sampling (8 channels / thread, 16B gathers) ----------
__global__ __launch_bounds__(256) void deform_kernel(
    const unsigned short* __restrict__ value_bf,
    const float* __restrict__ qout,
    const float* __restrict__ refp,
    const float* __restrict__ flow_fwd,
    const float* __restrict__ flow_bwd,
    unsigned short* __restrict__ dout)
{
    int gid = blockIdx.x * 256 + threadIdx.x;
    int d8 = gid & 3;
    int m = (gid >> 2) & 7;
    int q = (gid >> 5) & 4095;
    int b = gid >> 17;

    size_t bq = (size_t)b * HW_SZ + q;
    const float* qbase = qout + bq * 288;
    const float* al = qbase + 192 + m * 12;

    float lg[12];
    float mx = -1e30f;
    #pragma unroll
    for (int i = 0; i < 12; i++) { lg[i] = al[i]; mx = fmaxf(mx, lg[i]); }
    float s = 0.f;
    #pragma unroll
    for (int i = 0; i < 12; i++) { lg[i] = __expf(lg[i] - mx); s += lg[i]; }
    float inv = 1.f / s;

    const float* op = qbase + m * 24;
    const float* rp = refp + bq * 6;

    float acc[8];
    #pragma unroll
    for (int i = 0; i < 8; ++i) acc[i] = 0.f;

    #pragma unroll
    for (int t = 0; t < 3; t++) {
        float fx = 0.f, fy = 0.f;
        if (t == 0) {
            fx = flow_bwd[((b * 2 + 0) * 2 + 0) * HW_SZ + q];
            fy = flow_bwd[((b * 2 + 0) * 2 + 1) * HW_SZ + q];
        } else if (t == 2) {
            fx = flow_fwd[((b * 2 + 1) * 2 + 0) * HW_SZ + q];
            fy = flow_fwd[((b * 2 + 1) * 2 + 1) * HW_SZ + q];
        }
        float rx = rp[t * 2 + 0], ry = rp[t * 2 + 1];
        const unsigned short* vb =
            value_bf + (size_t)(b * 3 + t) * (HW_SZ * 256) + m * 32 + d8 * 8;
        #pragma unroll
        for (int pp = 0; pp < 4; pp++) {
            float ox = op[t * 8 + pp * 2 + 0] + fx;
            float oy = op[t * 8 + pp * 2 + 1] + fy;
            float aw = lg[t * 4 + pp] * inv;
            float x = rx * 64.f + ox - 0.5f;
            float y = ry * 64.f + oy - 0.5f;
            float x0f = floorf(x), y0f = floorf(y);
            float wx = x - x0f, wy = y - y0f;
            int x0 = (int)x0f, y0 = (int)y0f;
            int x1 = x0 + 1, y1 = y0 + 1;
            bool vx0 = (x0 >= 0) & (x0 < 64), vx1 = (x1 >= 0) & (x1 < 64);
            bool vy0 = (y0 >= 0) & (y0 < 64), vy1 = (y1 >= 0) & (y1 < 64);
            int cx0 = min(max(x0, 0), 63), cx1 = min(max(x1, 0), 63);
            int cy0 = min(max(y0, 0), 63), cy1 = min(max(y1, 0), 63);
            float w00 = (1.f - wx) * (1.f - wy) * ((vx0 & vy0) ? 1.f : 0.f) * aw;
            float w10 = wx * (1.f - wy) * ((vx1 & vy0) ? 1.f : 0.f) * aw;
            float w01 = (1.f - wx) * wy * ((vx0 & vy1) ? 1.f : 0.f) * aw;
            float w11 = wx * wy * ((vx1 & vy1) ? 1.f : 0.f) * aw;
            short8 v00 = *(const short8*)(vb + (cy0 * 64 + cx0) * 256);
            short8 v10 = *(const short8*)(vb + (cy0 * 64 + cx1) * 256);
            short8 v01 = *(const short8*)(vb + (cy1 * 64 + cx0) * 256);
            short8 v11 = *(const short8*)(vb + (cy1 * 64 + cx1) * 256);
            #pragma unroll
            for (int i = 0; i < 8; ++i) {
                acc[i] += w00 * bf2f((unsigned short)v00[i])
                        + w10 * bf2f((unsigned short)v10[i])
                        + w01 * bf2f((unsigned short)v01[i])
                        + w11 * bf2f((unsigned short)v11[i]);
            }
        }
    }
    unsigned pk[4];
    #pragma unroll
    for (int j = 0; j < 4; ++j)
        pk[j] = (unsigned)f2bf(acc[2 * j]) | ((unsigned)f2bf(acc[2 * j + 1]) << 16);
    uint4 o; o.x = pk[0]; o.y = pk[1]; o.z = pk[2]; o.w = pk[3];
    *(uint4*)(dout + bq * 256 + m * 32 + d8 * 8) = o;
}

extern "C" void kernel_launch(void* const* d_in, const int* in_sizes, int n_in,
                              void* d_out, int out_size, void* d_ws, size_t ws_size,
                              hipStream_t stream) {
    const float* query   = (const float*)d_in[0];
    const float* refp    = (const float*)d_in[1];
    const float* inflat  = (const float*)d_in[2];
    const float* flowf   = (const float*)d_in[6];
    const float* flowb   = (const float*)d_in[7];
    const float* w_value = (const float*)d_in[8];
    const float* b_value = (const float*)d_in[9];
    const float* w_off   = (const float*)d_in[10];
    const float* b_off   = (const float*)d_in[11];
    const float* w_attn  = (const float*)d_in[12];
    const float* b_attn  = (const float*)d_in[13];
    const float* w_out   = (const float*)d_in[14];
    const float* b_out   = (const float*)d_in[15];

    char* ws = (char*)d_ws;
    unsigned short* wpk_v    = (unsigned short*)(ws);                    // 1,179,648
    unsigned short* wpk_q    = (unsigned short*)(ws + 1179648);          // 5,308,416
    unsigned short* wpk_o    = (unsigned short*)(ws + 6488064);          // 1,179,648
    float*          qbias    = (float*)(ws + 7667712);                   // 1,536
    float*          zbuf     = (float*)(ws + 7669248);                   // 64
    unsigned short* value_bf = (unsigned short*)(ws + 7669760);          // 12,582,912
    unsigned short* qin_bf   = (unsigned short*)(ws + 20252672);         // 12,582,912
    unsigned short* vin_bf   = (unsigned short*)(ws + 32835584);         // 12,582,912

    const bool big = ws_size >= 54855680ull;
    float* qout = big ? (float*)(ws + 45418496)
                      : (float*)(ws + 32835584);   // small: over vin_bf
    unsigned short* dout_bf = big
        ? (unsigned short*)(ws + 1179648)          // over wpk_q (dead after convs)
        : (unsigned short*)(ws + 42272768);

    // 1) fused prep: transposes + weight repacks (incl. pad zero-fill) + biases
    prep_fused<<<dim3(6354), dim3(256), 0, stream>>>(
        inflat, query, vin_bf, qin_bf,
        w_value, w_off, w_attn, w_out, b_off, b_attn,
        wpk_v, wpk_q, wpk_o, qbias, zbuf);

    // 2) convs
    if (big) {
        // XCD-static schedule: 1-D grid, 8 XCD columns x 240 slots.
        conv_main<<<dim3(1920), dim3(128), 0, stream>>>(
            -1, vin_bf, wpk_v, b_value, value_bf, qin_bf, wpk_q, qbias, qout,
            (const unsigned short*)zbuf);
    } else {
        // small ws: qout aliases vin_bf -> run value conv first, then qconv
        conv_main<<<dim3(64, 12), dim3(128), 0, stream>>>(
            6, vin_bf, wpk_v, b_value, value_bf, qin_bf, wpk_q, qbias, qout,
            (const unsigned short*)zbuf);
        conv_main<<<dim3(64, 6), dim3(128), 0, stream>>>(
            0, vin_bf, wpk_v, b_value, value_bf, qin_bf, wpk_q, qbias, qout,
            (const unsigned short*)zbuf);
    }

    // 3) deform sampling (8 ch/thread, 16B gathers)
    deform_kernel<<<dim3(1024), dim3(256), 0, stream>>>(
        value_bf, qout, refp, flowf, flowb, dout_bf);

    // 4) output conv -> d_out (NCHW f32), XCD-static 1-D grid
    conv_out_k<<<dim3(256), dim3(128), 0, stream>>>(
        dout_bf, wpk_o, b_out, (float*)d_out, (const unsigned short*)zbuf);
}

// Round 2
// 326.659 us; speedup vs baseline: 1.1150x; 1.1150x over previous
//
#include <hip/hip_runtime.h>

// MSDeformAttn fusion, MI355X. Round 11: conv_core inner-loop reorder.
// R10 post-mortem: XCD pinning moved weights L3->L2 (FETCH 62->39MB) with ZERO
// time change -> conv is latency-bound, not BW-bound. In-order vmcnt analysis:
// old loop = [barrier][stage 7 loads][ldA 12 loads][tap0 waits ldA => drains
// stage too] -> full stage+ldA latency serialized before first MFMA, every kb.
// Fix: cross-iteration rolling ldA (taps 6..8 prefetch next kb's taps 0..2);
// tap0 now starts on registers drained by the barrier. Stage drain moves under
// ~250cy of MFMA cover at tap3. conv_core otherwise verbatim R4; XCD-static
// grids kept (neutral, better FETCH).
// B=2, T=3, C=256, H=W=64, M=8, P=4, DH=32.

#define HW_SZ 4096

typedef __attribute__((ext_vector_type(8))) short short8;
typedef __attribute__((ext_vector_type(4))) float f32x4;

__device__ __forceinline__ unsigned short f2bf(float f) {
    union { float f; unsigned u; } v; v.f = f;
    unsigned u = v.u;
    unsigned r = (u + 0x7FFFu + ((u >> 16) & 1u)) >> 16;
    return (unsigned short)r;
}
__device__ __forceinline__ float bf2f(unsigned short h) {
    union { unsigned u; float f; } v; v.u = ((unsigned)h) << 16;
    return v.f;
}

__device__ __forceinline__ void gld16(const void* g, void* l) {
    __builtin_amdgcn_global_load_lds(
        (const __attribute__((address_space(1))) unsigned*)g,
        (__attribute__((address_space(3))) unsigned*)l, 16, 0, 0);
}

// ---------------- fused prep: transposes + weight repacks + biases ----------------
// repack thread = (oc, kb, lg): reads 8 ic x 9 taps contiguous, writes 9 fragments
// to wpk [tap][ob][kb][64][8]. oc in [Cout, OBp*16) zero-fills (pad slots).
__device__ __forceinline__ void repack2(
    int g, const float* __restrict__ w0, const float* __restrict__ w1,
    int split, int Cout, int Cin, unsigned short* __restrict__ out, int OBp)
{
    int lg = g & 3; int rest = g >> 2;
    int KB = Cin >> 5;
    int kb = rest % KB; int oc = rest / KB;
    int ob = oc >> 4, l16 = oc & 15;
    if (oc >= Cout) {
        uint4 z; z.x = z.y = z.z = z.w = 0u;
        #pragma unroll
        for (int tap = 0; tap < 9; ++tap)
            *(uint4*)(out + (((size_t)tap * OBp + ob) * KB + kb) * 512 + (lg * 16 + l16) * 8) = z;
        return;
    }
    const float* src = (oc < split)
        ? (w0 + ((size_t)oc * Cin + kb * 32 + lg * 8) * 9)
        : (w1 + ((size_t)(oc - split) * Cin + kb * 32 + lg * 8) * 9);
    float v[8][9];
    #pragma unroll
    for (int i = 0; i < 8; ++i)
        #pragma unroll
        for (int t = 0; t < 9; ++t)
            v[i][t] = src[i * 9 + t];
    #pragma unroll
    for (int tap = 0; tap < 9; ++tap) {
        unsigned p[4];
        #pragma unroll
        for (int j = 0; j < 4; ++j)
            p[j] = (unsigned)f2bf(v[2 * j][tap]) | ((unsigned)f2bf(v[2 * j + 1][tap]) << 16);
        uint4 o; o.x = p[0]; o.y = p[1]; o.z = p[2]; o.w = p[3];
        *(uint4*)(out + (((size_t)tap * OBp + ob) * KB + kb) * 512 + (lg * 16 + l16) * 8) = o;
    }
}

__global__ __launch_bounds__(256) void prep_fused(
    const float* __restrict__ vin_src, const float* __restrict__ qin_src,
    unsigned short* __restrict__ vdst, unsigned short* __restrict__ qdst,
    const float* __restrict__ w_value, const float* __restrict__ w_off,
    const float* __restrict__ w_attn, const float* __restrict__ w_out,
    const float* __restrict__ b_off, const float* __restrict__ b_attn,
    unsigned short* __restrict__ wpk_v, unsigned short* __restrict__ wpk_q,
    unsigned short* __restrict__ wpk_o, float* __restrict__ qbias,
    float* __restrict__ zbuf)
{
    int bid = blockIdx.x;
    if (bid < 6144) {
        int y = bid & 63, z = bid >> 6;
        const float* in; unsigned short* out; int Cin, img, kb;
        if (z < 48) { img = z >> 3; kb = z & 7; in = vin_src; out = vdst; Cin = 256; }
        else { int h = z - 48; img = h / 24; kb = h % 24; in = qin_src; out = qdst; Cin = 768; }
        __shared__ float s[32][65];
        int t = threadIdx.x;
        int x = t & 63, ic4 = t >> 6;
        const float* ip = in + ((size_t)img * Cin + kb * 32) * HW_SZ + y * 64;
        #pragma unroll
        for (int i = 0; i < 8; ++i) {
            int icl = ic4 * 8 + i;
            s[icl][x] = ip[(size_t)icl * HW_SZ + x];
        }
        __syncthreads();
        int p = t >> 2, h4 = t & 3;
        unsigned v[4];
        #pragma unroll
        for (int j = 0; j < 4; ++j) {
            unsigned lo = f2bf(s[h4 * 8 + 2 * j][p]);
            unsigned hi = f2bf(s[h4 * 8 + 2 * j + 1][p]);
            v[j] = lo | (hi << 16);
        }
        uint4 o; o.x = v[0]; o.y = v[1]; o.z = v[2]; o.w = v[3];
        *(uint4*)(out + ((size_t)img * HW_SZ + y * 64 + p) * Cin + kb * 32 + h4 * 8) = o;
    } else {
        int g = (bid - 6144) * 256 + threadIdx.x;
        if (g < 8192) {
            repack2(g, w_value, w_value, 256, 256, 256, wpk_v, 16);
        } else if (g < 45056) {                                  // 384 oc x 24 kb x 4
            repack2(g - 8192, w_off, w_attn, 192, 288, 768, wpk_q, 24);
        } else if (g < 53248) {
            repack2(g - 45056, w_out, w_out, 256, 256, 256, wpk_o, 16);
        } else {
            int i = g - 53248;
            if (i < 16) zbuf[i] = 0.f;
            if (i < 384) {
                float v = 0.f;
                if (i < 192) v = b_off[i]; else if (i < 288) v = b_attn[i - 192];
                qbias[i] = v;
            }
        }
    }
}

// ---------------- MFMA conv core (R4 + cross-iteration weight prefetch) --------
// Block: 128 thr = 2 waves; wave wv = oc half. Tile: 128 oc x 64 px (row y0).
// LDS: 2 buffers x [3 rows][4 icg][66 cols] 16B units = 2 x 12672 B.
// Weight frags: rolling 3-tap register prefetch; taps 6..8 of kb prefetch
// taps 0..2 of kb+1 so tap0 never waits on VMEM after the barrier.
__device__ __forceinline__ void conv_core(
    const unsigned short* __restrict__ gin,
    const unsigned short* __restrict__ wpk,   // [9][OBp][KB][64][8]
    const float* __restrict__ bias,
    const unsigned short* __restrict__ zbuf,
    void* __restrict__ outp,
    int Cin, int KB, int OBp, int Cout, int mb, int y0, int outmode, int img,
    unsigned short* sbuf)
{
    const int tid = threadIdx.x;
    const int wv = tid >> 6, lane = tid & 63;
    const int l16 = lane & 15, lg = lane >> 4;
    const int obBase = mb * 8 + wv * 4;

    // precompute staging sources; wave wv takes issues ii = 2i+wv (13 total)
    const unsigned short* sptr[7];
    int okk[7];
    #pragma unroll
    for (int i = 0; i < 7; ++i) {
        int ii = 2 * i + wv;
        int r = ii * 64 + lane;
        sptr[i] = zbuf; okk[i] = 0;
        if (ii < 13 && r < 792) {
            int rr = r / 264;
            int rem = r - rr * 264;
            int icg = rem / 66;
            int cc = rem - icg * 66;
            int gy = y0 - 1 + rr, gx = cc - 1;
            if ((unsigned)gy < 64u && (unsigned)gx < 64u) {
                sptr[i] = gin + ((size_t)(gy * 64 + gx)) * Cin + icg * 8;
                okk[i] = 1;
            }
        }
    }

    f32x4 acc[4][4];
    #pragma unroll
    for (int a = 0; a < 4; ++a)
        #pragma unroll
        for (int b = 0; b < 4; ++b)
            acc[a][b] = (f32x4){0.f, 0.f, 0.f, 0.f};

    auto stage = [&](int kb, unsigned short* sb) {
        #pragma unroll
        for (int i = 0; i < 7; ++i) {
            int ii = 2 * i + wv;
            int r = ii * 64 + lane;
            if (ii < 13 && r < 792) {
                const unsigned short* s = sptr[i] + (okk[i] ? (size_t)kb * 32 : 0);
                gld16(s, sb + (size_t)ii * 64 * 8);
            }
        }
    };

    short8 afr[3][4];
    auto ldA = [&](int kb, int tap, int slot) {
        const unsigned short* wp =
            wpk + (((size_t)tap * OBp + obBase) * KB + kb) * 512;
        #pragma unroll
        for (int ob = 0; ob < 4; ++ob)
            afr[slot][ob] = *(const short8*)(wp + (size_t)ob * KB * 512 + lane * 8);
    };

    stage(0, sbuf);
    ldA(0, 0, 0); ldA(0, 1, 1); ldA(0, 2, 2);   // prologue; drained by 1st barrier
    for (int kb = 0; kb < KB; ++kb) {
        __syncthreads();                       // buffer kb ready; prefetched afr
                                               // slots 0..2 for kb retired here
        if (kb + 1 < KB) stage(kb + 1, sbuf + ((kb + 1) & 1) * 6336);
        const unsigned short* cb = sbuf + (kb & 1) * 6336;
        const int kn = (kb + 1 < KB) ? kb + 1 : kb;   // clamp: tail loads discarded
        #pragma unroll
        for (int tap = 0; tap < 9; ++tap) {
            const int ky = tap / 3, kx = tap % 3;
            const int slot = tap % 3;
            short8 bfr[4];
            #pragma unroll
            for (int pt = 0; pt < 4; ++pt)
                bfr[pt] = *(const short8*)(cb + (ky * 264 + lg * 66 + kx + pt * 16 + l16) * 8);
            #pragma unroll
            for (int ob = 0; ob < 4; ++ob)
                #pragma unroll
                for (int pt = 0; pt < 4; ++pt)
                    acc[ob][pt] = __builtin_amdgcn_mfma_f32_16x16x32_bf16(
                        afr[slot][ob], bfr[pt], acc[ob][pt], 0, 0, 0);
            if (tap < 6) ldA(kb, tap + 3, slot);   // within-kb rolling
            else         ldA(kn, tap - 6, slot);   // cross-kb prefetch (taps 0..2)
        }
    }

    if (outmode == 2) {
        float* outf = (float*)outp + (size_t)img * 256 * HW_SZ + (size_t)y0 * 64;
        #pragma unroll
        for (int ob = 0; ob < 4; ++ob) {
            int obg = obBase + ob;
            #pragma unroll
            for (int r = 0; r < 4; ++r) {
                int oc = obg * 16 + lg * 4 + r;
                float bv = bias[oc];
                #pragma unroll
                for (int pt = 0; pt < 4; ++pt)
                    outf[(size_t)oc * HW_SZ + pt * 16 + l16] = acc[ob][pt][r] + bv;
            }
        }
    } else {
        __syncthreads();                       // LDS reads done; reuse for epilogue
        float* s_ep = (float*)sbuf + wv * 1088;  // per-wave 64px x 17
        for (int ob = 0; ob < 4; ++ob) {
            int obg = obBase + ob;
            if (obg * 16 >= Cout) continue;    // wave-uniform
            #pragma unroll
            for (int r = 0; r < 4; ++r) {
                float bv = bias ? bias[obg * 16 + lg * 4 + r] : 0.f;
                #pragma unroll
                for (int pt = 0; pt < 4; ++pt)
                    s_ep[(pt * 16 + l16) * 17 + lg * 4 + r] = acc[ob][pt][r] + bv;
            }
            size_t pxg = (size_t)img * HW_SZ + (size_t)y0 * 64 + lane;
            if (outmode == 1) {
                float* op = (float*)outp + pxg * 288 + obg * 16;
                #pragma unroll
                for (int jj = 0; jj < 4; ++jj) {
                    float4 t4;
                    t4.x = s_ep[lane * 17 + jj * 4 + 0];
                    t4.y = s_ep[lane * 17 + jj * 4 + 1];
                    t4.z = s_ep[lane * 17 + jj * 4 + 2];
                    t4.w = s_ep[lane * 17 + jj * 4 + 3];
                    *(float4*)(op + jj * 4) = t4;
                }
            } else {
                unsigned short* op = (unsigned short*)outp + pxg * 256 + obg * 16;
                unsigned v[8];
                #pragma unroll
                for (int j = 0; j < 8; ++j) {
                    unsigned lo = f2bf(s_ep[lane * 17 + 2 * j]);
                    unsigned hi = f2bf(s_ep[lane * 17 + 2 * j + 1]);
                    v[j] = lo | (hi << 16);
                }
                uint4 o0; o0.x = v[0]; o0.y = v[1]; o0.z = v[2]; o0.w = v[3];
                uint4 o1; o1.x = v[4]; o1.y = v[5]; o1.z = v[6]; o1.w = v[7];
                *(uint4*)(op) = o0;
                *(uint4*)(op + 8) = o1;
            }
        }
    }
}

// merged value+qconv.
// ybase >= 0 (legacy / small-ws path): g = ybase + blockIdx.y, y0 = blockIdx.x:
//   g in [0,6):  qconv  img=g/3, mb=g%3  (768->288, f32 pm)  -- heavy, first
//   g in [6,18): value  img=(g-6)>>1, mb=(g-6)&1 (256->256, bf16 pm)
// ybase < 0 (big path): XCD-static schedule, 1-D grid of 1920, assumes
//   blockIdx.x % 8 == XCD. XCD x in [0,6): all 64 rows of qconv group g=x
//   (weight slice 1.77MB pinned in that XCD's L2) + 48 value rows.
//   XCD 6,7: 240 value rows each. Traffic ~166MB/XCD, balanced.
__global__ __launch_bounds__(128, 2) void conv_main(
    int ybase,
    const unsigned short* __restrict__ vin, const unsigned short* __restrict__ wv_,
    const float* __restrict__ bv, unsigned short* __restrict__ vout,
    const unsigned short* __restrict__ qin, const unsigned short* __restrict__ wq_,
    const float* __restrict__ bq, float* __restrict__ qout,
    const unsigned short* __restrict__ zbuf)
{
    __shared__ __align__(16) unsigned short sbuf[2 * 6336];
    int g, y0;
    if (ybase < 0) {
        int xcd = blockIdx.x & 7, idx = blockIdx.x >> 3;   // grid = 1920 = 8*240
        if (xcd < 6) {
            if (idx < 64) { g = xcd; y0 = idx; }           // qconv group x, row idx
            else if (idx < 112) {                          // 48 value rows
                int v = xcd * 48 + (idx - 64);
                g = 6 + (v >> 6); y0 = v & 63;
            } else {
                return;                                    // idle pad block
            }
        } else {                                           // 240 value rows each
            int v = 288 + (xcd - 6) * 240 + idx;
            g = 6 + (v >> 6); y0 = v & 63;
        }
    } else {
        g = ybase + blockIdx.y;
        y0 = blockIdx.x;
    }
    if (g < 6) {
        int img = g / 3, mb = g - img * 3;
        conv_core(qin + (size_t)img * HW_SZ * 768, wq_, bq, zbuf, (void*)qout,
                  768, 24, 24, 288, mb, y0, 1, img, sbuf);
    } else {
        int h = g - 6; int img = h >> 1, mb = h & 1;
        conv_core(vin + (size_t)img * HW_SZ * 256, wv_, bv, zbuf, (void*)vout,
                  256, 8, 16, 256, mb, y0, 0, img, sbuf);
    }
}

// out conv: 1-D grid of 256, XCD-static: xcd pair shares one (img,mb) group,
// each xcd covers 32 rows. NCHW f32 -> d_out.
__global__ __launch_bounds__(128, 2) void conv_out_k(
    const unsigned short* __restrict__ din, const unsigned short* __restrict__ wo_,
    const float* __restrict__ bo, float* __restrict__ outp,
    const unsigned short* __restrict__ zbuf)
{
    __shared__ __align__(16) unsigned short sbuf[2 * 6336];
    int xcd = blockIdx.x & 7, idx = blockIdx.x >> 3;       // idx 0..31
    int g = xcd >> 1;                                      // 0..3
    int y0 = (xcd & 1) * 32 + idx;
    int img = g >> 1, mb = g & 1;
    conv_core(din + (size_t)img * HW_SZ * 256, wo_, bo, zbuf, (void*)outp,
              256, 8, 16, 256, mb, y0, 2, img, sbuf);
}

// ---------------- deform sampling (8 channels / thread, 16B gathers) ----------
__global__ __launch_bounds__(256) void deform_kernel(
    const unsigned short* __restrict__ value_bf,
    const float* __restrict__ qout,
    const float* __restrict__ refp,
    const float* __restrict__ flow_fwd,
    const float* __restrict__ flow_bwd,
    unsigned short* __restrict__ dout)
{
    int gid = blockIdx.x * 256 + threadIdx.x;
    int d8 = gid & 3;
    int m = (gid >> 2) & 7;
    int q = (gid >> 5) & 4095;
    int b = gid >> 17;

    size_t bq = (size_t)b * HW_SZ + q;
    const float* qbase = qout + bq * 288;
    const float* al = qbase + 192 + m * 12;

    float lg[12];
    float mx = -1e30f;
    #pragma unroll
    for (int i = 0; i < 12; i++) { lg[i] = al[i]; mx = fmaxf(mx, lg[i]); }
    float s = 0.f;
    #pragma unroll
    for (int i = 0; i < 12; i++) { lg[i] = __expf(lg[i] - mx); s += lg[i]; }
    float inv = 1.f / s;

    const float* op = qbase + m * 24;
    const float* rp = refp + bq * 6;

    float acc[8];
    #pragma unroll
    for (int i = 0; i < 8; ++i) acc[i] = 0.f;

    #pragma unroll
    for (int t = 0; t < 3; t++) {
        float fx = 0.f, fy = 0.f;
        if (t == 0) {
            fx = flow_bwd[((b * 2 + 0) * 2 + 0) * HW_SZ + q];
            fy = flow_bwd[((b * 2 + 0) * 2 + 1) * HW_SZ + q];
        } else if (t == 2) {
            fx = flow_fwd[((b * 2 + 1) * 2 + 0) * HW_SZ + q];
            fy = flow_fwd[((b * 2 + 1) * 2 + 1) * HW_SZ + q];
        }
        float rx = rp[t * 2 + 0], ry = rp[t * 2 + 1];
        const unsigned short* vb =
            value_bf + (size_t)(b * 3 + t) * (HW_SZ * 256) + m * 32 + d8 * 8;
        #pragma unroll
        for (int pp = 0; pp < 4; pp++) {
            float ox = op[t * 8 + pp * 2 + 0] + fx;
            float oy = op[t * 8 + pp * 2 + 1] + fy;
            float aw = lg[t * 4 + pp] * inv;
            float x = rx * 64.f + ox - 0.5f;
            float y = ry * 64.f + oy - 0.5f;
            float x0f = floorf(x), y0f = floorf(y);
            float wx = x - x0f, wy = y - y0f;
            int x0 = (int)x0f, y0 = (int)y0f;
            int x1 = x0 + 1, y1 = y0 + 1;
            bool vx0 = (x0 >= 0) & (x0 < 64), vx1 = (x1 >= 0) & (x1 < 64);
            bool vy0 = (y0 >= 0) & (y0 < 64), vy1 = (y1 >= 0) & (y1 < 64);
            int cx0 = min(max(x0, 0), 63), cx1 = min(max(x1, 0), 63);
            int cy0 = min(max(y0, 0), 63), cy1 = min(max(y1, 0), 63);
            float w00 = (1.f - wx) * (1.f - wy) * ((vx0 & vy0) ? 1.f : 0.f) * aw;
            float w10 = wx * (1.f - wy) * ((vx1 & vy0) ? 1.f : 0.f) * aw;
            float w01 = (1.f - wx) * wy * ((vx0 & vy1) ? 1.f : 0.f) * aw;
            float w11 = wx * wy * ((vx1 & vy1) ? 1.f : 0.f) * aw;
            short8 v00 = *(const short8*)(vb + (cy0 * 64 + cx0) * 256);
            short8 v10 = *(const short8*)(vb + (cy0 * 64 + cx1) * 256);
            short8 v01 = *(const short8*)(vb + (cy1 * 64 + cx0) * 256);
            short8 v11 = *(const short8*)(vb + (cy1 * 64 + cx1) * 256);
            #pragma unroll
            for (int i = 0; i < 8; ++i) {
                acc[i] += w00 * bf2f((unsigned short)v00[i])
                        + w10 * bf2f((unsigned short)v10[i])
                        + w01 * bf2f((unsigned short)v01[i])
                        + w11 * bf2f((unsigned short)v11[i]);
            }
        }
    }
    unsigned pk[4];
    #pragma unroll
    for (int j = 0; j < 4; ++j)
        pk[j] = (unsigned)f2bf(acc[2 * j]) | ((unsigned)f2bf(acc[2 * j + 1]) << 16);
    uint4 o; o.x = pk[0]; o.y = pk[1]; o.z = pk[2]; o.w = pk[3];
    *(uint4*)(dout + bq * 256 + m * 32 + d8 * 8) = o;
}

extern "C" void kernel_launch(void* const* d_in, const int* in_sizes, int n_in,
                              void* d_out, int out_size, void* d_ws, size_t ws_size,
                              hipStream_t stream) {
    const float* query   = (const float*)d_in[0];
    const float* refp    = (const float*)d_in[1];
    const float* inflat  = (const float*)d_in[2];
    const float* flowf   = (const float*)d_in[6];
    const float* flowb   = (const float*)d_in[7];
    const float* w_value = (const float*)d_in[8];
    const float* b_value = (const float*)d_in[9];
    const float* w_off   = (const float*)d_in[10];
    const float* b_off   = (const float*)d_in[11];
    const float* w_attn  = (const float*)d_in[12];
    const float* b_attn  = (const float*)d_in[13];
    const float* w_out   = (const float*)d_in[14];
    const float* b_out   = (const float*)d_in[15];

    char* ws = (char*)d_ws;
    unsigned short* wpk_v    = (unsigned short*)(ws);                    // 1,179,648
    unsigned short* wpk_q    = (unsigned short*)(ws + 1179648);          // 5,308,416
    unsigned short* wpk_o    = (unsigned short*)(ws + 6488064);          // 1,179,648
    float*          qbias    = (float*)(ws + 7667712);                   // 1,536
    float*          zbuf     = (float*)(ws + 7669248);                   // 64
    unsigned short* value_bf = (unsigned short*)(ws + 7669760);          // 12,582,912
    unsigned short* qin_bf   = (unsigned short*)(ws + 20252672);         // 12,582,912
    unsigned short* vin_bf   = (unsigned short*)(ws + 32835584);         // 12,582,912

    const bool big = ws_size >= 54855680ull;
    float* qout = big ? (float*)(ws + 45418496)
                      : (float*)(ws + 32835584);   // small: over vin_bf
    unsigned short* dout_bf = big
        ? (unsigned short*)(ws + 1179648)          // over wpk_q (dead after convs)
        : (unsigned short*)(ws + 42272768);

    // 1) fused prep: transposes + weight repacks (incl. pad zero-fill) + biases
    prep_fused<<<dim3(6354), dim3(256), 0, stream>>>(
        inflat, query, vin_bf, qin_bf,
        w_value, w_off, w_attn, w_out, b_off, b_attn,
        wpk_v, wpk_q, wpk_o, qbias, zbuf);

    // 2) convs
    if (big) {
        // XCD-static schedule: 1-D grid, 8 XCD columns x 240 slots.
        conv_main<<<dim3(1920), dim3(128), 0, stream>>>(
            -1, vin_bf, wpk_v, b_value, value_bf, qin_bf, wpk_q, qbias, qout,
            (const unsigned short*)zbuf);
    } else {
        // small ws: qout aliases vin_bf -> run value conv first, then qconv
        conv_main<<<dim3(64, 12), dim3(128), 0, stream>>>(
            6, vin_bf, wpk_v, b_value, value_bf, qin_bf, wpk_q, qbias, qout,
            (const unsigned short*)zbuf);
        conv_main<<<dim3(64, 6), dim3(128), 0, stream>>>(
            0, vin_bf, wpk_v, b_value, value_bf, qin_bf, wpk_q, qbias, qout,
            (const unsigned short*)zbuf);
    }

    // 3) deform sampling (8 ch/thread, 16B gathers)
    deform_kernel<<<dim3(1024), dim3(256), 0, stream>>>(
        value_bf, qout, refp, flowf, flowb, dout_bf);

    // 4) output conv -> d_out (NCHW f32), XCD-static 1-D grid
    conv_out_k<<<dim3(256), dim3(128), 0, stream>>>(
        dout_bf, wpk_o, b_out, (float*)d_out, (const unsigned short*)zbuf);
}

// Round 3
// 321.197 us; speedup vs baseline: 1.1339x; 1.0170x over previous
//
#include <hip/hip_runtime.h>

// MSDeformAttn fusion, MI355X. Round 12: 4-wave conv blocks (256 thr).
// R11 post-mortem: prefetch fix gave 161->136us, but occupancy 14% => qconv
// phase runs 2 blocks/CU x 2 waves = 1 wave/SIMD: every ds_read->MFMA and
// barrier drain fully exposed. Fix: same tile (128oc x 64px), same grid, but
// 4 waves/block; wave = (oc-half wvO, px-half wvP) so per-CU LDS traffic is
// unchanged while waves/SIMD doubles (2 blocks/CU x 4 waves = 2/SIMD, from
// DIFFERENT blocks -> barriers don't co-stall). conv_out_k also now fills all
// 4 SIMDs at 1 block/CU. Dbuf/barrier/cross-kb-prefetch structure verbatim R11.
// B=2, T=3, C=256, H=W=64, M=8, P=4, DH=32.

#define HW_SZ 4096

typedef __attribute__((ext_vector_type(8))) short short8;
typedef __attribute__((ext_vector_type(4))) float f32x4;

__device__ __forceinline__ unsigned short f2bf(float f) {
    union { float f; unsigned u; } v; v.f = f;
    unsigned u = v.u;
    unsigned r = (u + 0x7FFFu + ((u >> 16) & 1u)) >> 16;
    return (unsigned short)r;
}
__device__ __forceinline__ float bf2f(unsigned short h) {
    union { unsigned u; float f; } v; v.u = ((unsigned)h) << 16;
    return v.f;
}

__device__ __forceinline__ void gld16(const void* g, void* l) {
    __builtin_amdgcn_global_load_lds(
        (const __attribute__((address_space(1))) unsigned*)g,
        (__attribute__((address_space(3))) unsigned*)l, 16, 0, 0);
}

// ---------------- fused prep: transposes + weight repacks + biases ----------------
__device__ __forceinline__ void repack2(
    int g, const float* __restrict__ w0, const float* __restrict__ w1,
    int split, int Cout, int Cin, unsigned short* __restrict__ out, int OBp)
{
    int lg = g & 3; int rest = g >> 2;
    int KB = Cin >> 5;
    int kb = rest % KB; int oc = rest / KB;
    int ob = oc >> 4, l16 = oc & 15;
    if (oc >= Cout) {
        uint4 z; z.x = z.y = z.z = z.w = 0u;
        #pragma unroll
        for (int tap = 0; tap < 9; ++tap)
            *(uint4*)(out + (((size_t)tap * OBp + ob) * KB + kb) * 512 + (lg * 16 + l16) * 8) = z;
        return;
    }
    const float* src = (oc < split)
        ? (w0 + ((size_t)oc * Cin + kb * 32 + lg * 8) * 9)
        : (w1 + ((size_t)(oc - split) * Cin + kb * 32 + lg * 8) * 9);
    float v[8][9];
    #pragma unroll
    for (int i = 0; i < 8; ++i)
        #pragma unroll
        for (int t = 0; t < 9; ++t)
            v[i][t] = src[i * 9 + t];
    #pragma unroll
    for (int tap = 0; tap < 9; ++tap) {
        unsigned p[4];
        #pragma unroll
        for (int j = 0; j < 4; ++j)
            p[j] = (unsigned)f2bf(v[2 * j][tap]) | ((unsigned)f2bf(v[2 * j + 1][tap]) << 16);
        uint4 o; o.x = p[0]; o.y = p[1]; o.z = p[2]; o.w = p[3];
        *(uint4*)(out + (((size_t)tap * OBp + ob) * KB + kb) * 512 + (lg * 16 + l16) * 8) = o;
    }
}

__global__ __launch_bounds__(256) void prep_fused(
    const float* __restrict__ vin_src, const float* __restrict__ qin_src,
    unsigned short* __restrict__ vdst, unsigned short* __restrict__ qdst,
    const float* __restrict__ w_value, const float* __restrict__ w_off,
    const float* __restrict__ w_attn, const float* __restrict__ w_out,
    const float* __restrict__ b_off, const float* __restrict__ b_attn,
    unsigned short* __restrict__ wpk_v, unsigned short* __restrict__ wpk_q,
    unsigned short* __restrict__ wpk_o, float* __restrict__ qbias,
    float* __restrict__ zbuf)
{
    int bid = blockIdx.x;
    if (bid < 6144) {
        int y = bid & 63, z = bid >> 6;
        const float* in; unsigned short* out; int Cin, img, kb;
        if (z < 48) { img = z >> 3; kb = z & 7; in = vin_src; out = vdst; Cin = 256; }
        else { int h = z - 48; img = h / 24; kb = h % 24; in = qin_src; out = qdst; Cin = 768; }
        __shared__ float s[32][65];
        int t = threadIdx.x;
        int x = t & 63, ic4 = t >> 6;
        const float* ip = in + ((size_t)img * Cin + kb * 32) * HW_SZ + y * 64;
        #pragma unroll
        for (int i = 0; i < 8; ++i) {
            int icl = ic4 * 8 + i;
            s[icl][x] = ip[(size_t)icl * HW_SZ + x];
        }
        __syncthreads();
        int p = t >> 2, h4 = t & 3;
        unsigned v[4];
        #pragma unroll
        for (int j = 0; j < 4; ++j) {
            unsigned lo = f2bf(s[h4 * 8 + 2 * j][p]);
            unsigned hi = f2bf(s[h4 * 8 + 2 * j + 1][p]);
            v[j] = lo | (hi << 16);
        }
        uint4 o; o.x = v[0]; o.y = v[1]; o.z = v[2]; o.w = v[3];
        *(uint4*)(out + ((size_t)img * HW_SZ + y * 64 + p) * Cin + kb * 32 + h4 * 8) = o;
    } else {
        int g = (bid - 6144) * 256 + threadIdx.x;
        if (g < 8192) {
            repack2(g, w_value, w_value, 256, 256, 256, wpk_v, 16);
        } else if (g < 45056) {                                  // 384 oc x 24 kb x 4
            repack2(g - 8192, w_off, w_attn, 192, 288, 768, wpk_q, 24);
        } else if (g < 53248) {
            repack2(g - 45056, w_out, w_out, 256, 256, 256, wpk_o, 16);
        } else {
            int i = g - 53248;
            if (i < 16) zbuf[i] = 0.f;
            if (i < 384) {
                float v = 0.f;
                if (i < 192) v = b_off[i]; else if (i < 288) v = b_attn[i - 192];
                qbias[i] = v;
            }
        }
    }
}

// ---------------- MFMA conv core (4-wave: oc-half x px-half per wave) ----------
// Block: 256 thr = 4 waves; wave = (wvO oc-half, wvP px-half). Tile: 128 oc x
// 64 px (row y0). LDS: 2 buffers x [3 rows][4 icg][66 cols] 16B = 2 x 12672 B.
// Weight frags: rolling 3-tap register prefetch; taps 6..8 of kb prefetch
// taps 0..2 of kb+1 so tap0 never waits on VMEM after the barrier.
__device__ __forceinline__ void conv_core(
    const unsigned short* __restrict__ gin,
    const unsigned short* __restrict__ wpk,   // [9][OBp][KB][64][8]
    const float* __restrict__ bias,
    const unsigned short* __restrict__ zbuf,
    void* __restrict__ outp,
    int Cin, int KB, int OBp, int Cout, int mb, int y0, int outmode, int img,
    unsigned short* sbuf)
{
    const int tid = threadIdx.x;
    const int wv = tid >> 6, lane = tid & 63;      // wv in 0..3
    const int l16 = lane & 15, lg = lane >> 4;
    const int wvO = wv & 1, wvP = wv >> 1;
    const int obBase = mb * 8 + wvO * 4;
    const int pxo = wvP * 2;                       // pt offset (units of 16 px)

    // precompute staging sources; wave wv takes issues ii = 4i+wv (13 total)
    const unsigned short* sptr[4];
    int okk[4];
    #pragma unroll
    for (int i = 0; i < 4; ++i) {
        int ii = 4 * i + wv;
        int r = ii * 64 + lane;
        sptr[i] = zbuf; okk[i] = 0;
        if (ii < 13 && r < 792) {
            int rr = r / 264;
            int rem = r - rr * 264;
            int icg = rem / 66;
            int cc = rem - icg * 66;
            int gy = y0 - 1 + rr, gx = cc - 1;
            if ((unsigned)gy < 64u && (unsigned)gx < 64u) {
                sptr[i] = gin + ((size_t)(gy * 64 + gx)) * Cin + icg * 8;
                okk[i] = 1;
            }
        }
    }

    f32x4 acc[4][2];
    #pragma unroll
    for (int a = 0; a < 4; ++a)
        #pragma unroll
        for (int b = 0; b < 2; ++b)
            acc[a][b] = (f32x4){0.f, 0.f, 0.f, 0.f};

    auto stage = [&](int kb, unsigned short* sb) {
        #pragma unroll
        for (int i = 0; i < 4; ++i) {
            int ii = 4 * i + wv;
            int r = ii * 64 + lane;
            if (ii < 13 && r < 792) {
                const unsigned short* s = sptr[i] + (okk[i] ? (size_t)kb * 32 : 0);
                gld16(s, sb + (size_t)ii * 64 * 8);
            }
        }
    };

    short8 afr[3][4];
    auto ldA = [&](int kb, int tap, int slot) {
        const unsigned short* wp =
            wpk + (((size_t)tap * OBp + obBase) * KB + kb) * 512;
        #pragma unroll
        for (int ob = 0; ob < 4; ++ob)
            afr[slot][ob] = *(const short8*)(wp + (size_t)ob * KB * 512 + lane * 8);
    };

    stage(0, sbuf);
    ldA(0, 0, 0); ldA(0, 1, 1); ldA(0, 2, 2);   // prologue; drained by 1st barrier
    for (int kb = 0; kb < KB; ++kb) {
        __syncthreads();                       // buffer kb ready; prefetched afr
                                               // slots 0..2 for kb retired here
        if (kb + 1 < KB) stage(kb + 1, sbuf + ((kb + 1) & 1) * 6336);
        const unsigned short* cb = sbuf + (kb & 1) * 6336;
        const int kn = (kb + 1 < KB) ? kb + 1 : kb;   // clamp: tail loads discarded
        #pragma unroll
        for (int tap = 0; tap < 9; ++tap) {
            const int ky = tap / 3, kx = tap % 3;
            const int slot = tap % 3;
            short8 bfr[2];
            #pragma unroll
            for (int pt = 0; pt < 2; ++pt)
                bfr[pt] = *(const short8*)(cb + (ky * 264 + lg * 66 + kx + (pxo + pt) * 16 + l16) * 8);
            #pragma unroll
            for (int ob = 0; ob < 4; ++ob)
                #pragma unroll
                for (int pt = 0; pt < 2; ++pt)
                    acc[ob][pt] = __builtin_amdgcn_mfma_f32_16x16x32_bf16(
                        afr[slot][ob], bfr[pt], acc[ob][pt], 0, 0, 0);
            if (tap < 6) ldA(kb, tap + 3, slot);   // within-kb rolling
            else         ldA(kn, tap - 6, slot);   // cross-kb prefetch (taps 0..2)
        }
    }

    if (outmode == 2) {
        float* outf = (float*)outp + (size_t)img * 256 * HW_SZ + (size_t)y0 * 64;
        #pragma unroll
        for (int ob = 0; ob < 4; ++ob) {
            int obg = obBase + ob;
            #pragma unroll
            for (int r = 0; r < 4; ++r) {
                int oc = obg * 16 + lg * 4 + r;
                float bv = bias[oc];
                #pragma unroll
                for (int pt = 0; pt < 2; ++pt)
                    outf[(size_t)oc * HW_SZ + (pxo + pt) * 16 + l16] = acc[ob][pt][r] + bv;
            }
        }
    } else {
        __syncthreads();                       // LDS reads done; reuse for epilogue
        float* s_ep = (float*)sbuf + wv * 544;   // per-wave 32px x 17
        for (int ob = 0; ob < 4; ++ob) {
            int obg = obBase + ob;
            if (obg * 16 >= Cout) continue;    // wave-uniform
            #pragma unroll
            for (int r = 0; r < 4; ++r) {
                float bv = bias ? bias[obg * 16 + lg * 4 + r] : 0.f;
                #pragma unroll
                for (int pt = 0; pt < 2; ++pt)
                    s_ep[(pt * 16 + l16) * 17 + lg * 4 + r] = acc[ob][pt][r] + bv;
            }
            if (lane < 32) {
                size_t pxg = (size_t)img * HW_SZ + (size_t)y0 * 64 + wvP * 32 + lane;
                if (outmode == 1) {
                    float* op = (float*)outp + pxg * 288 + obg * 16;
                    #pragma unroll
                    for (int jj = 0; jj < 4; ++jj) {
                        float4 t4;
                        t4.x = s_ep[lane * 17 + jj * 4 + 0];
                        t4.y = s_ep[lane * 17 + jj * 4 + 1];
                        t4.z = s_ep[lane * 17 + jj * 4 + 2];
                        t4.w = s_ep[lane * 17 + jj * 4 + 3];
                        *(float4*)(op + jj * 4) = t4;
                    }
                } else {
                    unsigned short* op = (unsigned short*)outp + pxg * 256 + obg * 16;
                    unsigned v[8];
                    #pragma unroll
                    for (int j = 0; j < 8; ++j) {
                        unsigned lo = f2bf(s_ep[lane * 17 + 2 * j]);
                        unsigned hi = f2bf(s_ep[lane * 17 + 2 * j + 1]);
                        v[j] = lo | (hi << 16);
                    }
                    uint4 o0; o0.x = v[0]; o0.y = v[1]; o0.z = v[2]; o0.w = v[3];
                    uint4 o1; o1.x = v[4]; o1.y = v[5]; o1.z = v[6]; o1.w = v[7];
                    *(uint4*)(op) = o0;
                    *(uint4*)(op + 8) = o1;
                }
            }
        }
    }
}

// merged value+qconv.
// ybase >= 0 (legacy / small-ws path): g = ybase + blockIdx.y, y0 = blockIdx.x.
// ybase < 0 (big path): XCD-static schedule, 1-D grid of 1920, assumes
//   blockIdx.x % 8 == XCD. XCD x in [0,6): all 64 rows of qconv group g=x
//   + 48 value rows. XCD 6,7: 240 value rows each.
__global__ __launch_bounds__(256, 2) void conv_main(
    int ybase,
    const unsigned short* __restrict__ vin, const unsigned short* __restrict__ wv_,
    const float* __restrict__ bv, unsigned short* __restrict__ vout,
    const unsigned short* __restrict__ qin, const unsigned short* __restrict__ wq_,
    const float* __restrict__ bq, float* __restrict__ qout,
    const unsigned short* __restrict__ zbuf)
{
    __shared__ __align__(16) unsigned short sbuf[2 * 6336];
    int g, y0;
    if (ybase < 0) {
        int xcd = blockIdx.x & 7, idx = blockIdx.x >> 3;   // grid = 1920 = 8*240
        if (xcd < 6) {
            if (idx < 64) { g = xcd; y0 = idx; }           // qconv group x, row idx
            else if (idx < 112) {                          // 48 value rows
                int v = xcd * 48 + (idx - 64);
                g = 6 + (v >> 6); y0 = v & 63;
            } else {
                return;                                    // idle pad block
            }
        } else {                                           // 240 value rows each
            int v = 288 + (xcd - 6) * 240 + idx;
            g = 6 + (v >> 6); y0 = v & 63;
        }
    } else {
        g = ybase + blockIdx.y;
        y0 = blockIdx.x;
    }
    if (g < 6) {
        int img = g / 3, mb = g - img * 3;
        conv_core(qin + (size_t)img * HW_SZ * 768, wq_, bq, zbuf, (void*)qout,
                  768, 24, 24, 288, mb, y0, 1, img, sbuf);
    } else {
        int h = g - 6; int img = h >> 1, mb = h & 1;
        conv_core(vin + (size_t)img * HW_SZ * 256, wv_, bv, zbuf, (void*)vout,
                  256, 8, 16, 256, mb, y0, 0, img, sbuf);
    }
}

// out conv: 1-D grid of 256, XCD-static: xcd pair shares one (img,mb) group,
// each xcd covers 32 rows. NCHW f32 -> d_out.
__global__ __launch_bounds__(256, 2) void conv_out_k(
    const unsigned short* __restrict__ din, const unsigned short* __restrict__ wo_,
    const float* __restrict__ bo, float* __restrict__ outp,
    const unsigned short* __restrict__ zbuf)
{
    __shared__ __align__(16) unsigned short sbuf[2 * 6336];
    int xcd = blockIdx.x & 7, idx = blockIdx.x >> 3;       // idx 0..31
    int g = xcd >> 1;                                      // 0..3
    int y0 = (xcd & 1) * 32 + idx;
    int img = g >> 1, mb = g & 1;
    conv_core(din + (size_t)img * HW_SZ * 256, wo_, bo, zbuf, (void*)outp,
              256, 8, 16, 256, mb, y0, 2, img, sbuf);
}

// ---------------- deform sampling (8 channels / thread, 16B gathers) ----------
__global__ __launch_bounds__(256) void deform_kernel(
    const unsigned short* __restrict__ value_bf,
    const float* __restrict__ qout,
    const float* __restrict__ refp,
    const float* __restrict__ flow_fwd,
    const float* __restrict__ flow_bwd,
    unsigned short* __restrict__ dout)
{
    int gid = blockIdx.x * 256 + threadIdx.x;
    int d8 = gid & 3;
    int m = (gid >> 2) & 7;
    int q = (gid >> 5) & 4095;
    int b = gid >> 17;

    size_t bq = (size_t)b * HW_SZ + q;
    const float* qbase = qout + bq * 288;
    const float* al = qbase + 192 + m * 12;

    float lg[12];
    float mx = -1e30f;
    #pragma unroll
    for (int i = 0; i < 12; i++) { lg[i] = al[i]; mx = fmaxf(mx, lg[i]); }
    float s = 0.f;
    #pragma unroll
    for (int i = 0; i < 12; i++) { lg[i] = __expf(lg[i] - mx); s += lg[i]; }
    float inv = 1.f / s;

    const float* op = qbase + m * 24;
    const float* rp = refp + bq * 6;

    float acc[8];
    #pragma unroll
    for (int i = 0; i < 8; ++i) acc[i] = 0.f;

    #pragma unroll
    for (int t = 0; t < 3; t++) {
        float fx = 0.f, fy = 0.f;
        if (t == 0) {
            fx = flow_bwd[((b * 2 + 0) * 2 + 0) * HW_SZ + q];
            fy = flow_bwd[((b * 2 + 0) * 2 + 1) * HW_SZ + q];
        } else if (t == 2) {
            fx = flow_fwd[((b * 2 + 1) * 2 + 0) * HW_SZ + q];
            fy = flow_fwd[((b * 2 + 1) * 2 + 1) * HW_SZ + q];
        }
        float rx = rp[t * 2 + 0], ry = rp[t * 2 + 1];
        const unsigned short* vb =
            value_bf + (size_t)(b * 3 + t) * (HW_SZ * 256) + m * 32 + d8 * 8;
        #pragma unroll
        for (int pp = 0; pp < 4; pp++) {
            float ox = op[t * 8 + pp * 2 + 0] + fx;
            float oy = op[t * 8 + pp * 2 + 1] + fy;
            float aw = lg[t * 4 + pp] * inv;
            float x = rx * 64.f + ox - 0.5f;
            float y = ry * 64.f + oy - 0.5f;
            float x0f = floorf(x), y0f = floorf(y);
            float wx = x - x0f, wy = y - y0f;
            int x0 = (int)x0f, y0 = (int)y0f;
            int x1 = x0 + 1, y1 = y0 + 1;
            bool vx0 = (x0 >= 0) & (x0 < 64), vx1 = (x1 >= 0) & (x1 < 64);
            bool vy0 = (y0 >= 0) & (y0 < 64), vy1 = (y1 >= 0) & (y1 < 64);
            int cx0 = min(max(x0, 0), 63), cx1 = min(max(x1, 0), 63);
            int cy0 = min(max(y0, 0), 63), cy1 = min(max(y1, 0), 63);
            float w00 = (1.f - wx) * (1.f - wy) * ((vx0 & vy0) ? 1.f : 0.f) * aw;
            float w10 = wx * (1.f - wy) * ((vx1 & vy0) ? 1.f : 0.f) * aw;
            float w01 = (1.f - wx) * wy * ((vx0 & vy1) ? 1.f : 0.f) * aw;
            float w11 = wx * wy * ((vx1 & vy1) ? 1.f : 0.f) * aw;
            short8 v00 = *(const short8*)(vb + (cy0 * 64 + cx0) * 256);
            short8 v10 = *(const short8*)(vb + (cy0 * 64 + cx1) * 256);
            short8 v01 = *(const short8*)(vb + (cy1 * 64 + cx0) * 256);
            short8 v11 = *(const short8*)(vb + (cy1 * 64 + cx1) * 256);
            #pragma unroll
            for (int i = 0; i < 8; ++i) {
                acc[i] += w00 * bf2f((unsigned short)v00[i])
                        + w10 * bf2f((unsigned short)v10[i])
                        + w01 * bf2f((unsigned short)v01[i])
                        + w11 * bf2f((unsigned short)v11[i]);
            }
        }
    }
    unsigned pk[4];
    #pragma unroll
    for (int j = 0; j < 4; ++j)
        pk[j] = (unsigned)f2bf(acc[2 * j]) | ((unsigned)f2bf(acc[2 * j + 1]) << 16);
    uint4 o; o.x = pk[0]; o.y = pk[1]; o.z = pk[2]; o.w = pk[3];
    *(uint4*)(dout + bq * 256 + m * 32 + d8 * 8) = o;
}

extern "C" void kernel_launch(void* const* d_in, const int* in_sizes, int n_in,
                              void* d_out, int out_size, void* d_ws, size_t ws_size,
                              hipStream_t stream) {
    const float* query   = (const float*)d_in[0];
    const float* refp    = (const float*)d_in[1];
    const float* inflat  = (const float*)d_in[2];
    const float* flowf   = (const float*)d_in[6];
    const float* flowb   = (const float*)d_in[7];
    const float* w_value = (const float*)d_in[8];
    const float* b_value = (const float*)d_in[9];
    const float* w_off   = (const float*)d_in[10];
    const float* b_off   = (const float*)d_in[11];
    const float* w_attn  = (const float*)d_in[12];
    const float* b_attn  = (const float*)d_in[13];
    const float* w_out   = (const float*)d_in[14];
    const float* b_out   = (const float*)d_in[15];

    char* ws = (char*)d_ws;
    unsigned short* wpk_v    = (unsigned short*)(ws);                    // 1,179,648
    unsigned short* wpk_q    = (unsigned short*)(ws + 1179648);          // 5,308,416
    unsigned short* wpk_o    = (unsigned short*)(ws + 6488064);          // 1,179,648
    float*          qbias    = (float*)(ws + 7667712);                   // 1,536
    float*          zbuf     = (float*)(ws + 7669248);                   // 64
    unsigned short* value_bf = (unsigned short*)(ws + 7669760);          // 12,582,912
    unsigned short* qin_bf   = (unsigned short*)(ws + 20252672);         // 12,582,912
    unsigned short* vin_bf   = (unsigned short*)(ws + 32835584);         // 12,582,912

    const bool big = ws_size >= 54855680ull;
    float* qout = big ? (float*)(ws + 45418496)
                      : (float*)(ws + 32835584);   // small: over vin_bf
    unsigned short* dout_bf = big
        ? (unsigned short*)(ws + 1179648)          // over wpk_q (dead after convs)
        : (unsigned short*)(ws + 42272768);

    // 1) fused prep: transposes + weight repacks (incl. pad zero-fill) + biases
    prep_fused<<<dim3(6354), dim3(256), 0, stream>>>(
        inflat, query, vin_bf, qin_bf,
        w_value, w_off, w_attn, w_out, b_off, b_attn,
        wpk_v, wpk_q, wpk_o, qbias, zbuf);

    // 2) convs
    if (big) {
        // XCD-static schedule: 1-D grid, 8 XCD columns x 240 slots.
        conv_main<<<dim3(1920), dim3(256), 0, stream>>>(
            -1, vin_bf, wpk_v, b_value, value_bf, qin_bf, wpk_q, qbias, qout,
            (const unsigned short*)zbuf);
    } else {
        // small ws: qout aliases vin_bf -> run value conv first, then qconv
        conv_main<<<dim3(64, 12), dim3(256), 0, stream>>>(
            6, vin_bf, wpk_v, b_value, value_bf, qin_bf, wpk_q, qbias, qout,
            (const unsigned short*)zbuf);
        conv_main<<<dim3(64, 6), dim3(256), 0, stream>>>(
            0, vin_bf, wpk_v, b_value, value_bf, qin_bf, wpk_q, qbias, qout,
            (const unsigned short*)zbuf);
    }

    // 3) deform sampling (8 ch/thread, 16B gathers)
    deform_kernel<<<dim3(1024), dim3(256), 0, stream>>>(
        value_bf, qout, refp, flowf, flowb, dout_bf);

    // 4) output conv -> d_out (NCHW f32), XCD-static 1-D grid
    conv_out_k<<<dim3(256), dim3(256), 0, stream>>>(
        dout_bf, wpk_o, b_out, (float*)d_out, (const unsigned short*)zbuf);
}

// Round 4
// 266.681 us; speedup vs baseline: 1.3657x; 1.2044x over previous
//
#include <hip/hip_runtime.h>

// MSDeformAttn fusion, MI355X. Round 13: ob-quarter wave split (zero afr dup).
// R12 post-mortem: occupancy doubled (2 waves/SIMD) but time flat at 135us.
// Cause: R12's (wvO,wvP) split duplicated afr weight loads 2x -> per-CU VMEM
// 321 KB per kb-slot = ~5000cy at the ~64 B/cy TA/L1 ceiling == observed slot
// time. R11 had low traffic but 1 wave/SIMD (latency-exposed, same 5.4k cy).
// Fix: 4 waves, wave wv owns 2 ob x 4 pt -> afr disjoint across waves:
// VMEM/slot 321->174 KB (~2700cy) AND 2 waves/SIMD retained. bfr LDS reads
// double (288 b128/slot, ~2500cy) - LDS pipe has headroom. Grids, XCD-static
// schedule, dbuf, cross-kb prefetch, barriers: verbatim R12.
// B=2, T=3, C=256, H=W=64, M=8, P=4, DH=32.

#define HW_SZ 4096

typedef __attribute__((ext_vector_type(8))) short short8;
typedef __attribute__((ext_vector_type(4))) float f32x4;

__device__ __forceinline__ unsigned short f2bf(float f) {
    union { float f; unsigned u; } v; v.f = f;
    unsigned u = v.u;
    unsigned r = (u + 0x7FFFu + ((u >> 16) & 1u)) >> 16;
    return (unsigned short)r;
}
__device__ __forceinline__ float bf2f(unsigned short h) {
    union { unsigned u; float f; } v; v.u = ((unsigned)h) << 16;
    return v.f;
}

__device__ __forceinline__ void gld16(const void* g, void* l) {
    __builtin_amdgcn_global_load_lds(
        (const __attribute__((address_space(1))) unsigned*)g,
        (__attribute__((address_space(3))) unsigned*)l, 16, 0, 0);
}

// ---------------- fused prep: transposes + weight repacks + biases ----------------
__device__ __forceinline__ void repack2(
    int g, const float* __restrict__ w0, const float* __restrict__ w1,
    int split, int Cout, int Cin, unsigned short* __restrict__ out, int OBp)
{
    int lg = g & 3; int rest = g >> 2;
    int KB = Cin >> 5;
    int kb = rest % KB; int oc = rest / KB;
    int ob = oc >> 4, l16 = oc & 15;
    if (oc >= Cout) {
        uint4 z; z.x = z.y = z.z = z.w = 0u;
        #pragma unroll
        for (int tap = 0; tap < 9; ++tap)
            *(uint4*)(out + (((size_t)tap * OBp + ob) * KB + kb) * 512 + (lg * 16 + l16) * 8) = z;
        return;
    }
    const float* src = (oc < split)
        ? (w0 + ((size_t)oc * Cin + kb * 32 + lg * 8) * 9)
        : (w1 + ((size_t)(oc - split) * Cin + kb * 32 + lg * 8) * 9);
    float v[8][9];
    #pragma unroll
    for (int i = 0; i < 8; ++i)
        #pragma unroll
        for (int t = 0; t < 9; ++t)
            v[i][t] = src[i * 9 + t];
    #pragma unroll
    for (int tap = 0; tap < 9; ++tap) {
        unsigned p[4];
        #pragma unroll
        for (int j = 0; j < 4; ++j)
            p[j] = (unsigned)f2bf(v[2 * j][tap]) | ((unsigned)f2bf(v[2 * j + 1][tap]) << 16);
        uint4 o; o.x = p[0]; o.y = p[1]; o.z = p[2]; o.w = p[3];
        *(uint4*)(out + (((size_t)tap * OBp + ob) * KB + kb) * 512 + (lg * 16 + l16) * 8) = o;
    }
}

__global__ __launch_bounds__(256) void prep_fused(
    const float* __restrict__ vin_src, const float* __restrict__ qin_src,
    unsigned short* __restrict__ vdst, unsigned short* __restrict__ qdst,
    const float* __restrict__ w_value, const float* __restrict__ w_off,
    const float* __restrict__ w_attn, const float* __restrict__ w_out,
    const float* __restrict__ b_off, const float* __restrict__ b_attn,
    unsigned short* __restrict__ wpk_v, unsigned short* __restrict__ wpk_q,
    unsigned short* __restrict__ wpk_o, float* __restrict__ qbias,
    float* __restrict__ zbuf)
{
    int bid = blockIdx.x;
    if (bid < 6144) {
        int y = bid & 63, z = bid >> 6;
        const float* in; unsigned short* out; int Cin, img, kb;
        if (z < 48) { img = z >> 3; kb = z & 7; in = vin_src; out = vdst; Cin = 256; }
        else { int h = z - 48; img = h / 24; kb = h % 24; in = qin_src; out = qdst; Cin = 768; }
        __shared__ float s[32][65];
        int t = threadIdx.x;
        int x = t & 63, ic4 = t >> 6;
        const float* ip = in + ((size_t)img * Cin + kb * 32) * HW_SZ + y * 64;
        #pragma unroll
        for (int i = 0; i < 8; ++i) {
            int icl = ic4 * 8 + i;
            s[icl][x] = ip[(size_t)icl * HW_SZ + x];
        }
        __syncthreads();
        int p = t >> 2, h4 = t & 3;
        unsigned v[4];
        #pragma unroll
        for (int j = 0; j < 4; ++j) {
            unsigned lo = f2bf(s[h4 * 8 + 2 * j][p]);
            unsigned hi = f2bf(s[h4 * 8 + 2 * j + 1][p]);
            v[j] = lo | (hi << 16);
        }
        uint4 o; o.x = v[0]; o.y = v[1]; o.z = v[2]; o.w = v[3];
        *(uint4*)(out + ((size_t)img * HW_SZ + y * 64 + p) * Cin + kb * 32 + h4 * 8) = o;
    } else {
        int g = (bid - 6144) * 256 + threadIdx.x;
        if (g < 8192) {
            repack2(g, w_value, w_value, 256, 256, 256, wpk_v, 16);
        } else if (g < 45056) {                                  // 384 oc x 24 kb x 4
            repack2(g - 8192, w_off, w_attn, 192, 288, 768, wpk_q, 24);
        } else if (g < 53248) {
            repack2(g - 45056, w_out, w_out, 256, 256, 256, wpk_o, 16);
        } else {
            int i = g - 53248;
            if (i < 16) zbuf[i] = 0.f;
            if (i < 384) {
                float v = 0.f;
                if (i < 192) v = b_off[i]; else if (i < 288) v = b_attn[i - 192];
                qbias[i] = v;
            }
        }
    }
}

// ---------------- MFMA conv core (4-wave: wave = 2-ob quarter, 4 pt) ----------
// Block: 256 thr = 4 waves; wave wv owns obBase = mb*8 + wv*2 (2 ob) over all
// 64 px (4 pt). afr loads are DISJOINT across waves (no duplicated VMEM).
// Tile: 128 oc x 64 px (row y0). LDS: 2 buf x [3 rows][4 icg][66 cols] 16B.
// Weight frags: rolling 3-tap register prefetch; taps 6..8 of kb prefetch
// taps 0..2 of kb+1 so tap0 never waits on VMEM after the barrier.
__device__ __forceinline__ void conv_core(
    const unsigned short* __restrict__ gin,
    const unsigned short* __restrict__ wpk,   // [9][OBp][KB][64][8]
    const float* __restrict__ bias,
    const unsigned short* __restrict__ zbuf,
    void* __restrict__ outp,
    int Cin, int KB, int OBp, int Cout, int mb, int y0, int outmode, int img,
    unsigned short* sbuf)
{
    const int tid = threadIdx.x;
    const int wv = tid >> 6, lane = tid & 63;      // wv in 0..3 = ob-quarter
    const int l16 = lane & 15, lg = lane >> 4;
    const int obBase = mb * 8 + wv * 2;

    // precompute staging sources; wave wv takes issues ii = 4i+wv (13 total)
    const unsigned short* sptr[4];
    int okk[4];
    #pragma unroll
    for (int i = 0; i < 4; ++i) {
        int ii = 4 * i + wv;
        int r = ii * 64 + lane;
        sptr[i] = zbuf; okk[i] = 0;
        if (ii < 13 && r < 792) {
            int rr = r / 264;
            int rem = r - rr * 264;
            int icg = rem / 66;
            int cc = rem - icg * 66;
            int gy = y0 - 1 + rr, gx = cc - 1;
            if ((unsigned)gy < 64u && (unsigned)gx < 64u) {
                sptr[i] = gin + ((size_t)(gy * 64 + gx)) * Cin + icg * 8;
                okk[i] = 1;
            }
        }
    }

    f32x4 acc[2][4];
    #pragma unroll
    for (int a = 0; a < 2; ++a)
        #pragma unroll
        for (int b = 0; b < 4; ++b)
            acc[a][b] = (f32x4){0.f, 0.f, 0.f, 0.f};

    auto stage = [&](int kb, unsigned short* sb) {
        #pragma unroll
        for (int i = 0; i < 4; ++i) {
            int ii = 4 * i + wv;
            int r = ii * 64 + lane;
            if (ii < 13 && r < 792) {
                const unsigned short* s = sptr[i] + (okk[i] ? (size_t)kb * 32 : 0);
                gld16(s, sb + (size_t)ii * 64 * 8);
            }
        }
    };

    short8 afr[3][2];
    auto ldA = [&](int kb, int tap, int slot) {
        const unsigned short* wp =
            wpk + (((size_t)tap * OBp + obBase) * KB + kb) * 512;
        #pragma unroll
        for (int ob = 0; ob < 2; ++ob)
            afr[slot][ob] = *(const short8*)(wp + (size_t)ob * KB * 512 + lane * 8);
    };

    stage(0, sbuf);
    ldA(0, 0, 0); ldA(0, 1, 1); ldA(0, 2, 2);   // prologue; drained by 1st barrier
    for (int kb = 0; kb < KB; ++kb) {
        __syncthreads();                       // buffer kb ready; prefetched afr
                                               // slots 0..2 for kb retired here
        if (kb + 1 < KB) stage(kb + 1, sbuf + ((kb + 1) & 1) * 6336);
        const unsigned short* cb = sbuf + (kb & 1) * 6336;
        const int kn = (kb + 1 < KB) ? kb + 1 : kb;   // clamp: tail loads discarded
        #pragma unroll
        for (int tap = 0; tap < 9; ++tap) {
            const int ky = tap / 3, kx = tap % 3;
            const int slot = tap % 3;
            short8 bfr[4];
            #pragma unroll
            for (int pt = 0; pt < 4; ++pt)
                bfr[pt] = *(const short8*)(cb + (ky * 264 + lg * 66 + kx + pt * 16 + l16) * 8);
            #pragma unroll
            for (int ob = 0; ob < 2; ++ob)
                #pragma unroll
                for (int pt = 0; pt < 4; ++pt)
                    acc[ob][pt] = __builtin_amdgcn_mfma_f32_16x16x32_bf16(
                        afr[slot][ob], bfr[pt], acc[ob][pt], 0, 0, 0);
            if (tap < 6) ldA(kb, tap + 3, slot);   // within-kb rolling
            else         ldA(kn, tap - 6, slot);   // cross-kb prefetch (taps 0..2)
        }
    }

    if (outmode == 2) {
        float* outf = (float*)outp + (size_t)img * 256 * HW_SZ + (size_t)y0 * 64;
        #pragma unroll
        for (int ob = 0; ob < 2; ++ob) {
            int obg = obBase + ob;
            #pragma unroll
            for (int r = 0; r < 4; ++r) {
                int oc = obg * 16 + lg * 4 + r;
                float bv = bias[oc];
                #pragma unroll
                for (int pt = 0; pt < 4; ++pt)
                    outf[(size_t)oc * HW_SZ + pt * 16 + l16] = acc[ob][pt][r] + bv;
            }
        }
    } else {
        __syncthreads();                       // LDS reads done; reuse for epilogue
        float* s_ep = (float*)sbuf + wv * 1088;  // per-wave 64px x 17 floats
        for (int ob = 0; ob < 2; ++ob) {
            int obg = obBase + ob;
            if (obg * 16 >= Cout) continue;    // wave-uniform
            #pragma unroll
            for (int r = 0; r < 4; ++r) {
                float bv = bias ? bias[obg * 16 + lg * 4 + r] : 0.f;
                #pragma unroll
                for (int pt = 0; pt < 4; ++pt)
                    s_ep[(pt * 16 + l16) * 17 + lg * 4 + r] = acc[ob][pt][r] + bv;
            }
            size_t pxg = (size_t)img * HW_SZ + (size_t)y0 * 64 + lane;
            if (outmode == 1) {
                float* op = (float*)outp + pxg * 288 + obg * 16;
                #pragma unroll
                for (int jj = 0; jj < 4; ++jj) {
                    float4 t4;
                    t4.x = s_ep[lane * 17 + jj * 4 + 0];
                    t4.y = s_ep[lane * 17 + jj * 4 + 1];
                    t4.z = s_ep[lane * 17 + jj * 4 + 2];
                    t4.w = s_ep[lane * 17 + jj * 4 + 3];
                    *(float4*)(op + jj * 4) = t4;
                }
            } else {
                unsigned short* op = (unsigned short*)outp + pxg * 256 + obg * 16;
                unsigned v[8];
                #pragma unroll
                for (int j = 0; j < 8; ++j) {
                    unsigned lo = f2bf(s_ep[lane * 17 + 2 * j]);
                    unsigned hi = f2bf(s_ep[lane * 17 + 2 * j + 1]);
                    v[j] = lo | (hi << 16);
                }
                uint4 o0; o0.x = v[0]; o0.y = v[1]; o0.z = v[2]; o0.w = v[3];
                uint4 o1; o1.x = v[4]; o1.y = v[5]; o1.z = v[6]; o1.w = v[7];
                *(uint4*)(op) = o0;
                *(uint4*)(op + 8) = o1;
            }
        }
    }
}

// merged value+qconv.
// ybase >= 0 (legacy / small-ws path): g = ybase + blockIdx.y, y0 = blockIdx.x.
// ybase < 0 (big path): XCD-static schedule, 1-D grid of 1920, assumes
//   blockIdx.x % 8 == XCD. XCD x in [0,6): all 64 rows of qconv group g=x
//   + 48 value rows. XCD 6,7: 240 value rows each.
__global__ __launch_bounds__(256, 2) void conv_main(
    int ybase,
    const unsigned short* __restrict__ vin, const unsigned short* __restrict__ wv_,
    const float* __restrict__ bv, unsigned short* __restrict__ vout,
    const unsigned short* __restrict__ qin, const unsigned short* __restrict__ wq_,
    const float* __restrict__ bq, float* __restrict__ qout,
    const unsigned short* __restrict__ zbuf)
{
    __shared__ __align__(16) unsigned short sbuf[2 * 6336];
    int g, y0;
    if (ybase < 0) {
        int xcd = blockIdx.x & 7, idx = blockIdx.x >> 3;   // grid = 1920 = 8*240
        if (xcd < 6) {
            if (idx < 64) { g = xcd; y0 = idx; }           // qconv group x, row idx
            else if (idx < 112) {                          // 48 value rows
                int v = xcd * 48 + (idx - 64);
                g = 6 + (v >> 6); y0 = v & 63;
            } else {
                return;                                    // idle pad block
            }
        } else {                                           // 240 value rows each
            int v = 288 + (xcd - 6) * 240 + idx;
            g = 6 + (v >> 6); y0 = v & 63;
        }
    } else {
        g = ybase + blockIdx.y;
        y0 = blockIdx.x;
    }
    if (g < 6) {
        int img = g / 3, mb = g - img * 3;
        conv_core(qin + (size_t)img * HW_SZ * 768, wq_, bq, zbuf, (void*)qout,
                  768, 24, 24, 288, mb, y0, 1, img, sbuf);
    } else {
        int h = g - 6; int img = h >> 1, mb = h & 1;
        conv_core(vin + (size_t)img * HW_SZ * 256, wv_, bv, zbuf, (void*)vout,
                  256, 8, 16, 256, mb, y0, 0, img, sbuf);
    }
}

// out conv: 1-D grid of 256, XCD-static: xcd pair shares one (img,mb) group,
// each xcd covers 32 rows. NCHW f32 -> d_out.
__global__ __launch_bounds__(256, 2) void conv_out_k(
    const unsigned short* __restrict__ din, const unsigned short* __restrict__ wo_,
    const float* __restrict__ bo, float* __restrict__ outp,
    const unsigned short* __restrict__ zbuf)
{
    __shared__ __align__(16) unsigned short sbuf[2 * 6336];
    int xcd = blockIdx.x & 7, idx = blockIdx.x >> 3;       // idx 0..31
    int g = xcd >> 1;                                      // 0..3
    int y0 = (xcd & 1) * 32 + idx;
    int img = g >> 1, mb = g & 1;
    conv_core(din + (size_t)img * HW_SZ * 256, wo_, bo, zbuf, (void*)outp,
              256, 8, 16, 256, mb, y0, 2, img, sbuf);
}

// ---------------- deform sampling (8 channels / thread, 16B gathers) ----------
__global__ __launch_bounds__(256) void deform_kernel(
    const unsigned short* __restrict__ value_bf,
    const float* __restrict__ qout,
    const float* __restrict__ refp,
    const float* __restrict__ flow_fwd,
    const float* __restrict__ flow_bwd,
    unsigned short* __restrict__ dout)
{
    int gid = blockIdx.x * 256 + threadIdx.x;
    int d8 = gid & 3;
    int m = (gid >> 2) & 7;
    int q = (gid >> 5) & 4095;
    int b = gid >> 17;

    size_t bq = (size_t)b * HW_SZ + q;
    const float* qbase = qout + bq * 288;
    const float* al = qbase + 192 + m * 12;

    float lg[12];
    float mx = -1e30f;
    #pragma unroll
    for (int i = 0; i < 12; i++) { lg[i] = al[i]; mx = fmaxf(mx, lg[i]); }
    float s = 0.f;
    #pragma unroll
    for (int i = 0; i < 12; i++) { lg[i] = __expf(lg[i] - mx); s += lg[i]; }
    float inv = 1.f / s;

    const float* op = qbase + m * 24;
    const float* rp = refp + bq * 6;

    float acc[8];
    #pragma unroll
    for (int i = 0; i < 8; ++i) acc[i] = 0.f;

    #pragma unroll
    for (int t = 0; t < 3; t++) {
        float fx = 0.f, fy = 0.f;
        if (t == 0) {
            fx = flow_bwd[((b * 2 + 0) * 2 + 0) * HW_SZ + q];
            fy = flow_bwd[((b * 2 + 0) * 2 + 1) * HW_SZ + q];
        } else if (t == 2) {
            fx = flow_fwd[((b * 2 + 1) * 2 + 0) * HW_SZ + q];
            fy = flow_fwd[((b * 2 + 1) * 2 + 1) * HW_SZ + q];
        }
        float rx = rp[t * 2 + 0], ry = rp[t * 2 + 1];
        const unsigned short* vb =
            value_bf + (size_t)(b * 3 + t) * (HW_SZ * 256) + m * 32 + d8 * 8;
        #pragma unroll
        for (int pp = 0; pp < 4; pp++) {
            float ox = op[t * 8 + pp * 2 + 0] + fx;
            float oy = op[t * 8 + pp * 2 + 1] + fy;
            float aw = lg[t * 4 + pp] * inv;
            float x = rx * 64.f + ox - 0.5f;
            float y = ry * 64.f + oy - 0.5f;
            float x0f = floorf(x), y0f = floorf(y);
            float wx = x - x0f, wy = y - y0f;
            int x0 = (int)x0f, y0 = (int)y0f;
            int x1 = x0 + 1, y1 = y0 + 1;
            bool vx0 = (x0 >= 0) & (x0 < 64), vx1 = (x1 >= 0) & (x1 < 64);
            bool vy0 = (y0 >= 0) & (y0 < 64), vy1 = (y1 >= 0) & (y1 < 64);
            int cx0 = min(max(x0, 0), 63), cx1 = min(max(x1, 0), 63);
            int cy0 = min(max(y0, 0), 63), cy1 = min(max(y1, 0), 63);
            float w00 = (1.f - wx) * (1.f - wy) * ((vx0 & vy0) ? 1.f : 0.f) * aw;
            float w10 = wx * (1.f - wy) * ((vx1 & vy0) ? 1.f : 0.f) * aw;
            float w01 = (1.f - wx) * wy * ((vx0 & vy1) ? 1.f : 0.f) * aw;
            float w11 = wx * wy * ((vx1 & vy1) ? 1.f : 0.f) * aw;
            short8 v00 = *(const short8*)(vb + (cy0 * 64 + cx0) * 256);
            short8 v10 = *(const short8*)(vb + (cy0 * 64 + cx1) * 256);
            short8 v01 = *(const short8*)(vb + (cy1 * 64 + cx0) * 256);
            short8 v11 = *(const short8*)(vb + (cy1 * 64 + cx1) * 256);
            #pragma unroll
            for (int i = 0; i < 8; ++i) {
                acc[i] += w00 * bf2f((unsigned short)v00[i])
                        + w10 * bf2f((unsigned short)v10[i])
                        + w01 * bf2f((unsigned short)v01[i])
                        + w11 * bf2f((unsigned short)v11[i]);
            }
        }
    }
    unsigned pk[4];
    #pragma unroll
    for (int j = 0; j < 4; ++j)
        pk[j] = (unsigned)f2bf(acc[2 * j]) | ((unsigned)f2bf(acc[2 * j + 1]) << 16);
    uint4 o; o.x = pk[0]; o.y = pk[1]; o.z = pk[2]; o.w = pk[3];
    *(uint4*)(dout + bq * 256 + m * 32 + d8 * 8) = o;
}

extern "C" void kernel_launch(void* const* d_in, const int* in_sizes, int n_in,
                              void* d_out, int out_size, void* d_ws, size_t ws_size,
                              hipStream_t stream) {
    const float* query   = (const float*)d_in[0];
    const float* refp    = (const float*)d_in[1];
    const float* inflat  = (const float*)d_in[2];
    const float* flowf   = (const float*)d_in[6];
    const float* flowb   = (const float*)d_in[7];
    const float* w_value = (const float*)d_in[8];
    const float* b_value = (const float*)d_in[9];
    const float* w_off   = (const float*)d_in[10];
    const float* b_off   = (const float*)d_in[11];
    const float* w_attn  = (const float*)d_in[12];
    const float* b_attn  = (const float*)d_in[13];
    const float* w_out   = (const float*)d_in[14];
    const float* b_out   = (const float*)d_in[15];

    char* ws = (char*)d_ws;
    unsigned short* wpk_v    = (unsigned short*)(ws);                    // 1,179,648
    unsigned short* wpk_q    = (unsigned short*)(ws + 1179648);          // 5,308,416
    unsigned short* wpk_o    = (unsigned short*)(ws + 6488064);          // 1,179,648
    float*          qbias    = (float*)(ws + 7667712);                   // 1,536
    float*          zbuf     = (float*)(ws + 7669248);                   // 64
    unsigned short* value_bf = (unsigned short*)(ws + 7669760);          // 12,582,912
    unsigned short* qin_bf   = (unsigned short*)(ws + 20252672);         // 12,582,912
    unsigned short* vin_bf   = (unsigned short*)(ws + 32835584);         // 12,582,912

    const bool big = ws_size >= 54855680ull;
    float* qout = big ? (float*)(ws + 45418496)
                      : (float*)(ws + 32835584);   // small: over vin_bf
    unsigned short* dout_bf = big
        ? (unsigned short*)(ws + 1179648)          // over wpk_q (dead after convs)
        : (unsigned short*)(ws + 42272768);

    // 1) fused prep: transposes + weight repacks (incl. pad zero-fill) + biases
    prep_fused<<<dim3(6354), dim3(256), 0, stream>>>(
        inflat, query, vin_bf, qin_bf,
        w_value, w_off, w_attn, w_out, b_off, b_attn,
        wpk_v, wpk_q, wpk_o, qbias, zbuf);

    // 2) convs
    if (big) {
        // XCD-static schedule: 1-D grid, 8 XCD columns x 240 slots.
        conv_main<<<dim3(1920), dim3(256), 0, stream>>>(
            -1, vin_bf, wpk_v, b_value, value_bf, qin_bf, wpk_q, qbias, qout,
            (const unsigned short*)zbuf);
    } else {
        // small ws: qout aliases vin_bf -> run value conv first, then qconv
        conv_main<<<dim3(64, 12), dim3(256), 0, stream>>>(
            6, vin_bf, wpk_v, b_value, value_bf, qin_bf, wpk_q, qbias, qout,
            (const unsigned short*)zbuf);
        conv_main<<<dim3(64, 6), dim3(256), 0, stream>>>(
            0, vin_bf, wpk_v, b_value, value_bf, qin_bf, wpk_q, qbias, qout,
            (const unsigned short*)zbuf);
    }

    // 3) deform sampling (8 ch/thread, 16B gathers)
    deform_kernel<<<dim3(1024), dim3(256), 0, stream>>>(
        value_bf, qout, refp, flowf, flowb, dout_bf);

    // 4) output conv -> d_out (NCHW f32), XCD-static 1-D grid
    conv_out_k<<<dim3(256), dim3(256), 0, stream>>>(
        dout_bf, wpk_o, b_out, (float*)d_out, (const unsigned short*)zbuf);
}